// Round 8
// baseline (347.992 us; speedup 1.0000x reference)
//
#include <hip/hip_runtime.h>
#include <stdint.h>

#define NVOX 400000
#define KTAPS 27
// CIN = COUT = 64

typedef __bf16 bf16x8 __attribute__((ext_vector_type(8)));
typedef float floatx16 __attribute__((ext_vector_type(16)));

__device__ __forceinline__ uint32_t f2bf(float f) {
  uint32_t u = __builtin_bit_cast(uint32_t, f);
  u += 0x7fffu + ((u >> 16) & 1u);
  return u >> 16;
}

__device__ __forceinline__ floatx16 zero16() {
  floatx16 z = {0.f,0.f,0.f,0.f,0.f,0.f,0.f,0.f,
                0.f,0.f,0.f,0.f,0.f,0.f,0.f,0.f};
  return z;
}

// Weight convert to FRAGMENT-MAJOR layout Wt2:
//   bf16 elem index = ((k*4 + kc)*2 + q)*512 + l*8 + e
//   holds W[k][ci][co] with ci = kc*16 + (l>>5)*8 + e, co = q*32 + (l&31).
// A wave's B-fragment load for (k,kc,q) is then ONE contiguous 1 KB chunk
// (lane l reads its own 16 B) -> perfectly coalesced, L1/L2-resident.
__global__ void k_wt(const float* __restrict__ W, unsigned short* __restrict__ Wt2) {
  int o = blockIdx.x * 256 + threadIdx.x;   // 27*4096 = 110592 elems, 432 blocks
  int k = o >> 12;
  int r = o & 4095;
  int kc = r >> 10;
  int q  = (r >> 9) & 1;
  int l  = (r >> 3) & 63;
  int e  = r & 7;
  int ci = kc * 16 + ((l >> 5) << 3) + e;
  int co = q * 32 + (l & 31);
  Wt2[o] = (unsigned short)f2bf(W[(k << 12) + ci * 64 + co]);
}

// Feats convert: fp32 -> bf16, 4 float4 per thread. Grid 6250 blocks.
__global__ void k_feats(const float4* __restrict__ F, uint2* __restrict__ Fb) {
  int i0 = blockIdx.x * 1024 + threadIdx.x;
#pragma unroll
  for (int j = 0; j < 4; ++j) {
    int i = i0 + j * 256;
    float4 v = F[i];
    uint2 o;
    o.x = f2bf(v.x) | (f2bf(v.y) << 16);
    o.y = f2bf(v.z) | (f2bf(v.w) << 16);
    Fb[i] = o;
  }
}

// R8: ZERO-LDS, ZERO-BARRIER main kernel.
// 4 independent waves per block; wave w owns rows [v0+w*64, +64) x all 64 couts.
// Per tap: 2 idx (prefetched), 8 masked A-gathers DIRECT into the 32x32x16
// MFMA A-fragment (lane l -> row l&31, k-slice (l>>5)*8 — 16 contiguous bytes
// of a feats row), 8 coalesced B-fragment loads from fragment-major Wt2,
// 16 MFMAs into AGPRs. The R7-dominant LDS round-trip (55% of CU cycles:
// 32KB write + 64KB read per block-tap) and all 54 barriers (each a vmcnt(0)
// drain) are deleted. Invalid rows: frag regs pre-zeroed, load exec-masked.
template<bool FB>
__global__ __launch_bounds__(256, 3) void k_conv(
    const float* __restrict__ feats,
    const unsigned short* __restrict__ featsb,
    const unsigned short* __restrict__ Wt2,    // fragment-major (see k_wt)
    const float* __restrict__ bias,
    const int* __restrict__ nbr,               // [27][NVOX]
    float* __restrict__ out) {                 // [NVOX][64]

  const int t = threadIdx.x;
  const int w = t >> 6;
  const int l = t & 63;
  const int half = l >> 5;
  const int lm = l & 31;

  // Bijective chunked XCD swizzle (m204): consecutive tiles -> same XCD L2.
  const int nwg = gridDim.x;
  const int q = nwg >> 3, r8 = nwg & 7;
  const int xcd = blockIdx.x & 7, hi = blockIdx.x >> 3;
  const int wg = (xcd < r8 ? xcd * (q + 1) : r8 * (q + 1) + (xcd - r8) * q) + hi;
  const int v0 = wg * 256;

  const int g0 = v0 + w * 64 + lm;   // this lane's group-0 voxel row
  const int g1 = g0 + 32;            // group-1 voxel row
  const bool vld0 = g0 < NVOX;
  const bool vld1 = g1 < NVOX;

  floatx16 acc00 = zero16(), acc01 = zero16(), acc10 = zero16(), acc11 = zero16();

  const unsigned short* WB = Wt2 + l * 8;   // lane's slot within each 1KB fragment
  const int hoff = half * 8;                // lane's 8-channel slice base

  int id0 = vld0 ? nbr[g0] : -1;
  int id1 = vld1 ? nbr[g1] : -1;

#pragma unroll 1
  for (int k = 0; k < KTAPS; ++k) {
    // ---- B fragments: 8 contiguous 1KB chunks (L1/L2-hot) ----
    const unsigned short* bp = WB + (k << 12);
    uint4 b00 = *(const uint4*)(bp);
    uint4 b01 = *(const uint4*)(bp + 512);
    uint4 b10 = *(const uint4*)(bp + 1024);
    uint4 b11 = *(const uint4*)(bp + 1536);
    uint4 b20 = *(const uint4*)(bp + 2048);
    uint4 b21 = *(const uint4*)(bp + 2560);
    uint4 b30 = *(const uint4*)(bp + 3072);
    uint4 b31 = *(const uint4*)(bp + 3584);

    // ---- A fragments: masked direct gather (invalid lanes: zero, no request) ----
    uint4 a00 = {0,0,0,0}, a01 = {0,0,0,0}, a02 = {0,0,0,0}, a03 = {0,0,0,0};
    uint4 a10 = {0,0,0,0}, a11 = {0,0,0,0}, a12 = {0,0,0,0}, a13 = {0,0,0,0};
    if (FB) {
      if (id0 >= 0) {
        const unsigned short* s = featsb + (size_t)id0 * 64 + hoff;
        a00 = *(const uint4*)(s);
        a01 = *(const uint4*)(s + 16);
        a02 = *(const uint4*)(s + 32);
        a03 = *(const uint4*)(s + 48);
      }
      if (id1 >= 0) {
        const unsigned short* s = featsb + (size_t)id1 * 64 + hoff;
        a10 = *(const uint4*)(s);
        a11 = *(const uint4*)(s + 16);
        a12 = *(const uint4*)(s + 32);
        a13 = *(const uint4*)(s + 48);
      }
    } else {
      if (id0 >= 0) {
        const float* s = feats + (size_t)id0 * 64 + hoff;
#define CVT(dst, p) do { float4 f0_ = *(const float4*)(p); float4 f1_ = *(const float4*)((p) + 4); \
        dst.x = f2bf(f0_.x) | (f2bf(f0_.y) << 16); dst.y = f2bf(f0_.z) | (f2bf(f0_.w) << 16);     \
        dst.z = f2bf(f1_.x) | (f2bf(f1_.y) << 16); dst.w = f2bf(f1_.z) | (f2bf(f1_.w) << 16); } while (0)
        CVT(a00, s); CVT(a01, s + 16); CVT(a02, s + 32); CVT(a03, s + 48);
      }
      if (id1 >= 0) {
        const float* s = feats + (size_t)id1 * 64 + hoff;
        CVT(a10, s); CVT(a11, s + 16); CVT(a12, s + 32); CVT(a13, s + 48);
#undef CVT
      }
    }

    // ---- prefetch next tap's indices (completes under the MFMA phase) ----
    if (k + 1 < KTAPS) {
      const int* nb = nbr + (size_t)(k + 1) * NVOX;
      id0 = vld0 ? nb[g0] : -1;
      id1 = vld1 ? nb[g1] : -1;
    }

    // ---- MFMA: 4 K-chunks of 16 channels ----
    acc00 = __builtin_amdgcn_mfma_f32_32x32x16_bf16(__builtin_bit_cast(bf16x8, a00), __builtin_bit_cast(bf16x8, b00), acc00, 0, 0, 0);
    acc01 = __builtin_amdgcn_mfma_f32_32x32x16_bf16(__builtin_bit_cast(bf16x8, a00), __builtin_bit_cast(bf16x8, b01), acc01, 0, 0, 0);
    acc10 = __builtin_amdgcn_mfma_f32_32x32x16_bf16(__builtin_bit_cast(bf16x8, a10), __builtin_bit_cast(bf16x8, b00), acc10, 0, 0, 0);
    acc11 = __builtin_amdgcn_mfma_f32_32x32x16_bf16(__builtin_bit_cast(bf16x8, a10), __builtin_bit_cast(bf16x8, b01), acc11, 0, 0, 0);
    acc00 = __builtin_amdgcn_mfma_f32_32x32x16_bf16(__builtin_bit_cast(bf16x8, a01), __builtin_bit_cast(bf16x8, b10), acc00, 0, 0, 0);
    acc01 = __builtin_amdgcn_mfma_f32_32x32x16_bf16(__builtin_bit_cast(bf16x8, a01), __builtin_bit_cast(bf16x8, b11), acc01, 0, 0, 0);
    acc10 = __builtin_amdgcn_mfma_f32_32x32x16_bf16(__builtin_bit_cast(bf16x8, a11), __builtin_bit_cast(bf16x8, b10), acc10, 0, 0, 0);
    acc11 = __builtin_amdgcn_mfma_f32_32x32x16_bf16(__builtin_bit_cast(bf16x8, a11), __builtin_bit_cast(bf16x8, b11), acc11, 0, 0, 0);
    acc00 = __builtin_amdgcn_mfma_f32_32x32x16_bf16(__builtin_bit_cast(bf16x8, a02), __builtin_bit_cast(bf16x8, b20), acc00, 0, 0, 0);
    acc01 = __builtin_amdgcn_mfma_f32_32x32x16_bf16(__builtin_bit_cast(bf16x8, a02), __builtin_bit_cast(bf16x8, b21), acc01, 0, 0, 0);
    acc10 = __builtin_amdgcn_mfma_f32_32x32x16_bf16(__builtin_bit_cast(bf16x8, a12), __builtin_bit_cast(bf16x8, b20), acc10, 0, 0, 0);
    acc11 = __builtin_amdgcn_mfma_f32_32x32x16_bf16(__builtin_bit_cast(bf16x8, a12), __builtin_bit_cast(bf16x8, b21), acc11, 0, 0, 0);
    acc00 = __builtin_amdgcn_mfma_f32_32x32x16_bf16(__builtin_bit_cast(bf16x8, a03), __builtin_bit_cast(bf16x8, b30), acc00, 0, 0, 0);
    acc01 = __builtin_amdgcn_mfma_f32_32x32x16_bf16(__builtin_bit_cast(bf16x8, a03), __builtin_bit_cast(bf16x8, b31), acc01, 0, 0, 0);
    acc10 = __builtin_amdgcn_mfma_f32_32x32x16_bf16(__builtin_bit_cast(bf16x8, a13), __builtin_bit_cast(bf16x8, b30), acc10, 0, 0, 0);
    acc11 = __builtin_amdgcn_mfma_f32_32x32x16_bf16(__builtin_bit_cast(bf16x8, a13), __builtin_bit_cast(bf16x8, b31), acc11, 0, 0, 0);
  }

  // ---- epilogue: C/D layout col=lane&31 (cout), row=(reg&3)+8*(reg>>2)+4*half ----
  float bv0 = bias[lm];
  float bv1 = bias[32 + lm];
#pragma unroll
  for (int reg = 0; reg < 16; ++reg) {
    int m = (reg & 3) + 8 * (reg >> 2) + 4 * half;
    int vm0 = v0 + w * 64 + m;
    int vm1 = vm0 + 32;
    if (vm0 < NVOX) {
      out[vm0 * 64 + lm]      = acc00[reg] + bv0;
      out[vm0 * 64 + 32 + lm] = acc01[reg] + bv1;
    }
    if (vm1 < NVOX) {
      out[vm1 * 64 + lm]      = acc10[reg] + bv0;
      out[vm1 * 64 + 32 + lm] = acc11[reg] + bv1;
    }
  }
}

extern "C" void kernel_launch(void* const* d_in, const int* in_sizes, int n_in,
                              void* d_out, int out_size, void* d_ws, size_t ws_size,
                              hipStream_t stream) {
  const float* feats  = (const float*)d_in[0];
  const float* weight = (const float*)d_in[1];
  const float* bias   = (const float*)d_in[2];
  const int*   nbr    = (const int*)d_in[3];
  float* out = (float*)d_out;

  unsigned short* Wt = (unsigned short*)d_ws;   // 221184 B (fragment-major)
  const size_t featsOff = 256 * 1024;
  const size_t fbytes = (size_t)NVOX * 64 * 2;  // 51.2 MB
  const bool bigws = ws_size >= featsOff + fbytes;

  k_wt<<<432, 256, 0, stream>>>(weight, Wt);

  const int grid = (NVOX + 255) / 256;  // 1563
  if (bigws) {
    unsigned short* Fb = (unsigned short*)((char*)d_ws + featsOff);
    k_feats<<<6250, 256, 0, stream>>>((const float4*)feats, (uint2*)Fb);
    k_conv<true><<<grid, 256, 0, stream>>>(feats, Fb, Wt, bias, nbr, out);
  } else {
    k_conv<false><<<grid, 256, 0, stream>>>(feats, nullptr, Wt, bias, nbr, out);
  }
}